// Round 1
// 1137.723 us; speedup vs baseline: 1.3106x; 1.3106x over previous
//
#include <hip/hip_runtime.h>
#include <stdint.h>

// Problem constants: C[8192,11008] = Xq*sx  @  ((W-off)*scl)^T, group=128
#define M_TOK 8192
#define K_IN  4096
#define N_OUT 11008

typedef float f32x4 __attribute__((ext_vector_type(4)));
typedef __bf16 bf16x8 __attribute__((ext_vector_type(8)));

typedef const uint32_t __attribute__((address_space(1)))* gas_ptr;
typedef uint32_t __attribute__((address_space(3)))* las_ptr;

__device__ __forceinline__ uint16_t f2bf(float f) {
  // round-to-nearest-even fp32 -> bf16 (inputs are finite normals)
  uint32_t u = __float_as_uint(f);
  return (uint16_t)((u + 0x7fffu + ((u >> 16) & 1u)) >> 16);
}

// ---- pass 1a: x_bf16[t,k] = bf16(qx[t,k] * sx[t]) ----
__global__ __launch_bounds__(256) void dequant_x_kernel(
    const float* __restrict__ qx, const float* __restrict__ sx,
    uint16_t* __restrict__ out) {
  int idx = blockIdx.x * 256 + threadIdx.x;   // float4 index; K=4096 -> 1024 f4/row
  int row = idx >> 10;
  float s = sx[row];
  float4 v = reinterpret_cast<const float4*>(qx)[idx];
  ushort4 o;
  o.x = f2bf(v.x * s);
  o.y = f2bf(v.y * s);
  o.z = f2bf(v.z * s);
  o.w = f2bf(v.w * s);
  reinterpret_cast<ushort4*>(out)[idx] = o;
}

// ---- pass 1b: w_bf16[o,k] = bf16((w[o,k] - off[o,k/128]) * scl[o,k/128]) ----
__global__ __launch_bounds__(256) void dequant_w_kernel(
    const float* __restrict__ w, const float* __restrict__ scl,
    const float* __restrict__ off, uint16_t* __restrict__ out) {
  int idx = blockIdx.x * 256 + threadIdx.x;   // float4 index
  int rg = idx >> 5;                          // (idx*4)/128 = row*32 + group
  float s = scl[rg];
  float o = off[rg];
  float4 v = reinterpret_cast<const float4*>(w)[idx];
  ushort4 u;
  u.x = f2bf((v.x - o) * s);
  u.y = f2bf((v.y - o) * s);
  u.z = f2bf((v.z - o) * s);
  u.w = f2bf((v.w - o) * s);
  reinterpret_cast<ushort4*>(out)[idx] = u;
}

// ---- pass 2: 256x256-tile, BK=64, 8-wave (2M x 4N), 8-phase pipelined GEMM ----
// C[M,N] = A[M,K] * B[N,K]^T, bf16 in / fp32 out.
// Schedule (m201 template): per phase {ds_read subtile ; 2x global_load_lds ;
// s_barrier ; lgkmcnt(0) ; setprio(1) 16xMFMA setprio(0) ; s_barrier}, with
// counted s_waitcnt vmcnt(6) only at phases 4/8 (3 stage-pairs stay in flight
// across barriers). Quadrant order per K-tile: (0,0),(0,1),(1,1),(1,0) with A
// fragments register-carried across 2 phases -> 28 ds_read_b128/wave/K-tile.
// LDS: sA[2][256][64], sB[2][256][64] bf16 = 128 KiB, 16B-chunk XOR swizzle
// (chunk c of row r at slot c^(r&7)) applied via pre-swizzled global source.
// B rows permuted in LDS: L = Nq*128 + bh*64 + wl*32 + r  <->
// global n-row = bh*128 + wl*64 + Nq*32 + r, so each stage unit is contiguous.
__global__ __launch_bounds__(512, 2) void gemm_bt_kernel(
    const uint16_t* __restrict__ A,   // [M,K] bf16 bits
    const uint16_t* __restrict__ B,   // [N,K] bf16 bits
    float* __restrict__ C) {          // [M,N] fp32
  constexpr int K = K_IN;
  constexpr int N = N_OUT;

  __shared__ __align__(128) uint16_t smem[65536];   // 128 KiB
  uint16_t* sA = smem;            // [2][256][64]
  uint16_t* sB = smem + 32768;    // [2][256][64] (row-permuted)

  const int tid  = threadIdx.x;
  const int lane = tid & 63;
  const int wave = tid >> 6;      // 0..7
  const int wm = wave >> 2;       // 0..1: M half of the tile
  const int wn = wave & 3;        // 0..3: N quarter of the tile

  // XCD-aware bijective swizzle: nwg = 43*32 = 1376 = 8*172.
  // XCD chunk = 4 M-rows x 43 N-cols, m-fastest within 4-wide band:
  // A panels (1MB) L2-resident and reused 43x; B panels reused 4x in L2,
  // each XCD sweeps B exactly once.
  const int bid = blockIdx.x;
  const int xcd = bid & 7;
  const int wic = bid >> 3;                      // 0..171
  const int blockM = ((xcd << 2) | (wic & 3)) << 8;
  const int blockN = (wic >> 2) << 8;

  f32x4 acc[8][4];
#pragma unroll
  for (int i = 0; i < 8; ++i)
#pragma unroll
    for (int j = 0; j < 4; ++j) acc[i][j] = {0.f, 0.f, 0.f, 0.f};

  // Per-thread staging source bases. One global_load_lds (per wave) moves
  // 64 lanes x 16B = 8 LDS rows; lane l covers row (wave*8 + l>>3), chunk
  // slot l&7 which holds global chunk (l&7)^(row&7)  [row&7 == l>>3].
  const int dr = lane >> 3;
  const int cg = (lane & 7) ^ dr;
  const int xw = wave * 8 + dr;                  // 0..63: row within a 64-row unit
  const uint16_t* aSrcBase = A + (size_t)(blockM + xw) * K + cg * 8;
  const uint16_t* bSrcBase =
      B + (size_t)(blockN + ((xw >> 5) << 6) + (xw & 31)) * K + cg * 8;

#define STAGE_A(TT, D, MQ)                                                      \
  do {                                                                          \
    _Pragma("unroll") for (int h_ = 0; h_ < 2; ++h_) {                          \
      __builtin_amdgcn_global_load_lds(                                         \
          (gas_ptr)(const void*)(aSrcBase +                                     \
                                 (size_t)(h_ * 128 + (MQ) * 64) * K +           \
                                 (size_t)(TT) * 64),                            \
          (las_ptr)(void*)(sA + (D) * 16384 +                                   \
                           (h_ * 128 + (MQ) * 64 + wave * 8) * 64),             \
          16, 0, 0);                                                            \
    }                                                                           \
  } while (0)

#define STAGE_B(TT, D, NQ)                                                      \
  do {                                                                          \
    _Pragma("unroll") for (int h_ = 0; h_ < 2; ++h_) {                          \
      __builtin_amdgcn_global_load_lds(                                         \
          (gas_ptr)(const void*)(bSrcBase +                                     \
                                 (size_t)(h_ * 128 + (NQ) * 32) * K +           \
                                 (size_t)(TT) * 64),                            \
          (las_ptr)(void*)(sB + (D) * 16384 +                                   \
                           ((NQ) * 128 + h_ * 64 + wave * 8) * 64),             \
          16, 0, 0);                                                            \
    }                                                                           \
  } while (0)

  bf16x8 af[4][2];   // A fragments, carried across 2 phases
  bf16x8 bfr[2][2];  // B fragments, per phase

#define READ_A(D, MQ)                                                           \
  do {                                                                          \
    _Pragma("unroll") for (int mi_ = 0; mi_ < 4; ++mi_) {                       \
      const uint16_t* pa_ =                                                     \
          sA + (D) * 16384 +                                                    \
          (wm * 128 + (MQ) * 64 + mi_ * 16 + (lane & 15)) * 64;                 \
      _Pragma("unroll") for (int ks_ = 0; ks_ < 2; ++ks_) {                     \
        const int kc_ = ks_ * 4 + (lane >> 4);                                  \
        af[mi_][ks_] = *reinterpret_cast<const bf16x8*>(                        \
            pa_ + ((kc_ ^ (lane & 7)) << 3));                                   \
      }                                                                         \
    }                                                                           \
  } while (0)

#define READ_B(D, NQ)                                                           \
  do {                                                                          \
    _Pragma("unroll") for (int ni_ = 0; ni_ < 2; ++ni_) {                       \
      const uint16_t* pb_ =                                                     \
          sB + (D) * 16384 +                                                    \
          ((NQ) * 128 + (wn >> 1) * 64 + (wn & 1) * 32 + ni_ * 16 +             \
           (lane & 15)) * 64;                                                   \
      _Pragma("unroll") for (int ks_ = 0; ks_ < 2; ++ks_) {                     \
        const int kc_ = ks_ * 4 + (lane >> 4);                                  \
        bfr[ni_][ks_] = *reinterpret_cast<const bf16x8*>(                       \
            pb_ + ((kc_ ^ (lane & 7)) << 3));                                   \
      }                                                                         \
    }                                                                           \
  } while (0)

#define DO_MFMA(MQ, NQ)                                                         \
  do {                                                                          \
    __builtin_amdgcn_s_setprio(1);                                              \
    _Pragma("unroll") for (int ks_ = 0; ks_ < 2; ++ks_)                         \
    _Pragma("unroll") for (int mi_ = 0; mi_ < 4; ++mi_)                         \
    _Pragma("unroll") for (int ni_ = 0; ni_ < 2; ++ni_)                         \
        acc[(MQ) * 4 + mi_][(NQ) * 2 + ni_] =                                   \
            __builtin_amdgcn_mfma_f32_16x16x32_bf16(                            \
                af[mi_][ks_], bfr[ni_][ks_],                                    \
                acc[(MQ) * 4 + mi_][(NQ) * 2 + ni_], 0, 0, 0);                  \
    __builtin_amdgcn_s_setprio(0);                                              \
  } while (0)

#define BAR    __builtin_amdgcn_s_barrier()
#define LGKM0  asm volatile("s_waitcnt lgkmcnt(0)" ::: "memory")
#define VMCNT6 asm volatile("s_waitcnt vmcnt(6)" ::: "memory")

  // ---- prologue: tile0 complete (4 pairs) + tile1 first 3 pairs ----
  STAGE_A(0, 0, 0);
  STAGE_B(0, 0, 0);
  STAGE_A(0, 0, 1);
  STAGE_B(0, 0, 1);
  STAGE_A(1, 1, 0);
  STAGE_B(1, 1, 1);
  STAGE_A(1, 1, 1);
  VMCNT6;  // oldest 8 loads (= tile0) landed; tile1's 6 may fly
  BAR;

  // ---- main loop: 32 iterations x 2 K-tiles ----
  for (int i = 0; i < 32; ++i) {
    const int t1 = 2 * i + 1;
    const int t2 = (2 * i + 2) & 63;  // wrap at the tail: dead-but-safe stages
    const int t3 = (2 * i + 3) & 63;

    // phase 1: tile 2i (dbuf0), quadrant (Mq0,Nq0); stage B-Nq0(t+1)->dbuf1
    READ_A(0, 0);
    READ_B(0, 0);
    STAGE_B(t1, 1, 0);
    BAR; LGKM0; DO_MFMA(0, 0); BAR;

    // phase 2: (Mq0,Nq1), af carried; stage A-Mq0(t+2)->dbuf0 (freed @ph1)
    READ_B(0, 1);
    STAGE_A(t2, 0, 0);
    BAR; LGKM0; DO_MFMA(0, 1); BAR;

    // phase 3: (Mq1,Nq1), bfr carried conceptually (re-read A only);
    // stage B-Nq1(t+2)->dbuf0 (freed @ph2)
    READ_A(0, 1);
    STAGE_B(t2, 0, 1);
    BAR; LGKM0; DO_MFMA(1, 1); BAR;

    // phase 4: (Mq1,Nq0); stage A-Mq1(t+2)->dbuf0 (freed @ph3); vmcnt gate
    READ_B(0, 0);
    STAGE_A(t2, 0, 1);
    VMCNT6;  // guarantees tile t+1 fully landed before ph5 (barrier globalizes)
    BAR; LGKM0; DO_MFMA(1, 0); BAR;

    // phase 5: tile 2i+1 (dbuf1), (Mq0,Nq0); stage B-Nq0(t+2)->dbuf0 (freed @ph4)
    READ_A(1, 0);
    READ_B(1, 0);
    STAGE_B(t2, 0, 0);
    BAR; LGKM0; DO_MFMA(0, 0); BAR;

    // phase 6: (Mq0,Nq1); stage A-Mq0(t+3)->dbuf1 (freed @ph5)
    READ_B(1, 1);
    STAGE_A(t3, 1, 0);
    BAR; LGKM0; DO_MFMA(0, 1); BAR;

    // phase 7: (Mq1,Nq1); stage B-Nq1(t+3)->dbuf1 (freed @ph6)
    READ_A(1, 1);
    STAGE_B(t3, 1, 1);
    BAR; LGKM0; DO_MFMA(1, 1); BAR;

    // phase 8: (Mq1,Nq0); stage A-Mq1(t+3)->dbuf1 (freed @ph7); vmcnt gate
    READ_B(1, 0);
    STAGE_A(t3, 1, 1);
    VMCNT6;  // tile t+2 fully landed before next ph1
    BAR; LGKM0; DO_MFMA(1, 0); BAR;
  }

  // ---- epilogue: C/D layout (16x16x32): col = lane&15, row = (lane>>4)*4+v
  const int crow0 = blockM + wm * 128 + (lane >> 4) * 4;
  const int ccol0 = blockN + wn * 64 + (lane & 15);
#pragma unroll
  for (int MI = 0; MI < 8; ++MI)
#pragma unroll
    for (int NI = 0; NI < 4; ++NI)
#pragma unroll
      for (int v = 0; v < 4; ++v)
        C[(size_t)(crow0 + MI * 16 + v) * N + (ccol0 + NI * 16)] =
            acc[MI][NI][v];

#undef STAGE_A
#undef STAGE_B
#undef READ_A
#undef READ_B
#undef DO_MFMA
#undef BAR
#undef LGKM0
#undef VMCNT6
}

extern "C" void kernel_launch(void* const* d_in, const int* in_sizes, int n_in,
                              void* d_out, int out_size, void* d_ws, size_t ws_size,
                              hipStream_t stream) {
  const float* qx   = (const float*)d_in[0];  // [8192, 4096]
  const float* sx   = (const float*)d_in[1];  // [8192, 1]
  const float* w    = (const float*)d_in[2];  // [11008, 4096]
  const float* wscl = (const float*)d_in[3];  // [11008, 32]
  const float* woff = (const float*)d_in[4];  // [11008, 32]
  float* out = (float*)d_out;                 // [8192, 11008]

  // workspace: A_bf16 (64 MiB) then B_bf16 (86 MiB)
  uint16_t* Abf = (uint16_t*)d_ws;
  uint16_t* Bbf = Abf + (size_t)M_TOK * K_IN;

  {
    int n4 = M_TOK * K_IN / 4;                 // 8,388,608
    dequant_x_kernel<<<n4 / 256, 256, 0, stream>>>(qx, sx, Abf);
  }
  {
    int n4 = (int)((size_t)N_OUT * K_IN / 4);  // 11,272,192
    dequant_w_kernel<<<n4 / 256, 256, 0, stream>>>(w, wscl, woff, Bbf);
  }
  {
    dim3 grid(1376);                           // (11008/256) * (8192/256) = 43*32
    gemm_bt_kernel<<<grid, 512, 0, stream>>>(Abf, Bbf, out);
  }
}